// Round 8
// baseline (3301.618 us; speedup 1.0000x reference)
//
#include <hip/hip_runtime.h>
#include <hip/hip_bf16.h>

// Problem constants
#define B_  64
#define T_  512
#define E_  256
#define H_  512
#define G4_ 2048
#define C_  4

typedef __attribute__((ext_vector_type(4))) float  f32x4;
typedef __attribute__((ext_vector_type(8))) __bf16 bf16x8;
typedef __attribute__((ext_vector_type(8))) short  short8;   // no HIP builtin 'short8'
typedef __attribute__((ext_vector_type(4))) short  s16x4;    // HIP predefines 'short4'

union V16 { f32x4 f; bf16x8 b; short8 s; };

__device__ __forceinline__ float sigmoid_(float x) { return 1.0f / (1.0f + __expf(-x)); }
__device__ __forceinline__ float tanh_(float x)    { return 1.0f - 2.0f / (__expf(2.0f * x) + 1.0f); }

// Deterministic RNE fp32 -> bf16
__device__ __forceinline__ short f2bf(float f) {
  union { float f; unsigned u; } v; v.f = f;
  return (short)((v.u + 0x7FFFu + ((v.u >> 16) & 1u)) >> 16);
}

// --- MALL-coherent ops (sc0 sc1: bypass L1+L2, meet at the coherent point).
//     r5-proven semantics; no XCD-placement assumptions anywhere. ---
__device__ __forceinline__ void st_u16_llc(void* p, unsigned v) {
  asm volatile("global_store_short %0, %1, off sc0 sc1" :: "v"(p), "v"(v) : "memory");
}
__device__ __forceinline__ void st_u32_llc(void* p, unsigned v) {
  asm volatile("global_store_dword %0, %1, off sc0 sc1" :: "v"(p), "v"(v) : "memory");
}
__device__ __forceinline__ void st_f32_llc(void* p, float v) {
  asm volatile("global_store_dword %0, %1, off sc0 sc1" :: "v"(p), "v"(v) : "memory");
}
__device__ __forceinline__ unsigned ld_u32_llc(const void* p) {
  unsigned v;
  asm volatile("global_load_dword %0, %1, off sc0 sc1\n\ts_waitcnt vmcnt(0)"
               : "=&v"(v) : "v"(p) : "memory");
  return v;
}
__device__ __forceinline__ f32x4 ld_b128_llc(const void* p) {
  f32x4 v;
  asm volatile("global_load_dwordx4 %0, %1, off sc0 sc1\n\ts_waitcnt vmcnt(0)"
               : "=&v"(v) : "v"(p) : "memory");
  return v;
}
// Fire-and-forget xg prefetch: 4 zero-extended u16 loads, NO waitcnt. The
// results are valid only after a later vmcnt(0) (the next step's poll) —
// consumed one full step after issue.
__device__ __forceinline__ void prefetch_xg(const short* p,
                                            unsigned* r0, unsigned* r1,
                                            unsigned* r2, unsigned* r3) {
  asm volatile(
      "global_load_ushort %0, %4, off\n\t"
      "global_load_ushort %1, %5, off\n\t"
      "global_load_ushort %2, %6, off\n\t"
      "global_load_ushort %3, %7, off"
      : "=&v"(*r0), "=&v"(*r1), "=&v"(*r2), "=&v"(*r3)
      : "v"(p), "v"(p + 32768), "v"(p + 65536), "v"(p + 98304)
      : "memory");
}

// ---------------------------------------------------------------------------
// Phase 1: xg[t][g][b][d] — unchanged from round 6 (proven).
// ---------------------------------------------------------------------------
__global__ __launch_bounds__(256, 1) void xg_kernel(
    const int* __restrict__ x, const float* __restrict__ emb,
    const float* __restrict__ W_ih,
    __hip_bfloat16* __restrict__ xg)
{
  const int t   = blockIdx.x;
  const int tid = threadIdx.x;
  __shared__ int s_idx[B_];
  __shared__ __hip_bfloat16 s_e[B_][E_ + 8];

  if (tid < B_) s_idx[tid] = x[tid * T_ + t];
  __syncthreads();
  {
    int b = tid >> 2, ch = tid & 3;
    const float* src = emb + (size_t)s_idx[b] * E_ + ch * 64;
    short* dst = (short*)&s_e[b][ch * 64];
#pragma unroll
    for (int i = 0; i < 16; i++) {
      f32x4 v = *(const f32x4*)(src + i * 4);
      s16x4 s;
      s[0] = f2bf(v[0]); s[1] = f2bf(v[1]); s[2] = f2bf(v[2]); s[3] = f2bf(v[3]);
      *(s16x4*)(dst + i * 4) = s;
    }
  }
  __syncthreads();

  const int wv   = tid >> 6;
  const int lane = tid & 63;
  const int ln15 = lane & 15, quad = lane >> 4;

  V16 breg[4][8];
#pragma unroll
  for (int nt = 0; nt < 4; nt++)
#pragma unroll
    for (int ks = 0; ks < 8; ks++)
      breg[nt][ks].f = *(const f32x4*)(&s_e[nt * 16 + ln15][quad * 8 + ks * 32]);

  const int gbase = wv * 512;
  const size_t base_t = (size_t)t * (G4_ * B_);
  for (int mt = 0; mt < 32; mt++) {
    const int grow = gbase + mt * 16 + ln15;
    const float* arow = W_ih + (size_t)grow * E_ + quad * 8;
    V16 areg[8];
#pragma unroll
    for (int ks = 0; ks < 8; ks++) {
      f32x4 lo = *(const f32x4*)(arow + ks * 32);
      f32x4 hi = *(const f32x4*)(arow + ks * 32 + 4);
      short8 s;
      s[0] = f2bf(lo[0]); s[1] = f2bf(lo[1]); s[2] = f2bf(lo[2]); s[3] = f2bf(lo[3]);
      s[4] = f2bf(hi[0]); s[5] = f2bf(hi[1]); s[6] = f2bf(hi[2]); s[7] = f2bf(hi[3]);
      areg[ks].s = s;
    }

    f32x4 acc[4];
#pragma unroll
    for (int nt = 0; nt < 4; nt++) acc[nt] = (f32x4){0.f, 0.f, 0.f, 0.f};
#pragma unroll
    for (int ks = 0; ks < 8; ks++)
#pragma unroll
      for (int nt = 0; nt < 4; nt++)
        acc[nt] = __builtin_amdgcn_mfma_f32_16x16x32_bf16(areg[ks].b, breg[nt][ks].b, acc[nt], 0, 0, 0);

    const int dbase = mt * 16 + quad * 4;
#pragma unroll
    for (int nt = 0; nt < 4; nt++) {
      const int batch = nt * 16 + ln15;
      s16x4 sv;
#pragma unroll
      for (int r = 0; r < 4; r++) sv[r] = f2bf(acc[nt][r]);
      *(s16x4*)((short*)xg + base_t + ((size_t)wv << 15) + ((size_t)batch << 9) + dbase) = sv;
    }
  }
}

// ---------------------------------------------------------------------------
// Phase 2: persistent recurrent kernel, 64 blocks x 1024 threads (16 waves).
// Group g = blk&7: 8 batches; dim-block pd = blk>>3: 64 dims -> 256 gate rows.
// All cross-block traffic via MALL (sc0 sc1) — no placement assumptions.
// Sync: PER-WAVE flags. Producer wave w (tid<512, w=tid>>6) owns batch g*8+w,
// 64 dims; after its h store it drains its own vmcnt and publishes
// ctl[g*64 + pd*8 + w] = t+1. Consumers fused-poll the flag covering their
// 16B h slice, then load it. 2 barriers/step (S1 post-staging, S2 post-s_pre):
// S1/S2 alone fence all LDS races (see analysis); no end-of-step barrier.
// xg prefetched one step ahead (raw ushort loads, absorbed by next poll's
// vmcnt(0)). Waves 8-15 only run MFMA between barriers.
// ---------------------------------------------------------------------------
__global__ __launch_bounds__(1024, 4) void lstm_kernel(
    const float* __restrict__ W_hh,
    const float* __restrict__ b_ih, const float* __restrict__ b_hh,
    const float* __restrict__ W_fc, const float* __restrict__ b_fc,
    const __hip_bfloat16* __restrict__ xg,
    unsigned int* ctl, __hip_bfloat16* hbuf /*[2][64][512]*/, float* hT,
    float* out)
{
  const int tid  = threadIdx.x;
  const int blk  = blockIdx.x;
  const int g    = blk & 7;        // batch group (8 batches)
  const int pd   = blk >> 3;       // dim slice [pd*64, +64)
  const int d0   = pd * 64;
  const int wv   = tid >> 6;
  const int lane = tid & 63;
  const int ln15 = lane & 15, quad = lane >> 4;

  __shared__ __hip_bfloat16 s_h[16][520];   // h_t: rows 0-7 = batches, 8-15 = zeros
  __shared__ float s_pre[4][8][68];         // [gate][batch][dim(+4 pad)]

  // Register-resident bf16 A fragments; wave wv -> gate wv>>2, dims (wv&3)*16+ln15
  V16 areg[16];
  {
    const int grow = (wv >> 2) * 512 + d0 + (wv & 3) * 16 + ln15;
    const float* ap = W_hh + (size_t)grow * H_ + quad * 8;
#pragma unroll
    for (int ks = 0; ks < 16; ks++) {
      f32x4 lo = *(const f32x4*)(ap + ks * 32);
      f32x4 hi = *(const f32x4*)(ap + ks * 32 + 4);
      short8 s;
      s[0] = f2bf(lo[0]); s[1] = f2bf(lo[1]); s[2] = f2bf(lo[2]); s[3] = f2bf(lo[3]);
      s[4] = f2bf(hi[0]); s[5] = f2bf(hi[1]); s[6] = f2bf(hi[2]); s[7] = f2bf(hi[3]);
      areg[ks].s = s;
    }
  }

  // Stager/gate-cell mapping (tid<512): batch-local nb = wave index, dim nd
  const int nb = tid >> 6;         // 0..7  (== wv for tid<512)
  const int nd = tid & 63;         // 0..63
  const int gb = g * 8 + nb;       // global batch
  const int dg = d0 + nd;          // global h-dim
  float bias_i = 0.f, bias_f = 0.f, bias_g = 0.f, bias_o = 0.f;
  if (tid < 512) {
    bias_i = b_ih[dg]        + b_hh[dg];
    bias_f = b_ih[512 + dg]  + b_hh[512 + dg];
    bias_g = b_ih[1024 + dg] + b_hh[1024 + dg];
    bias_o = b_ih[1536 + dg] + b_hh[1536 + dg];
  } else {
    // zero s_h rows 8..15 once (N-tile cols 8..15 multiply against zeros)
    const int i2 = tid - 512;
    *(f32x4*)&s_h[8 + (i2 >> 6)][(i2 & 63) * 8] = (f32x4){0.f, 0.f, 0.f, 0.f};
  }
  float c = 0.0f;

  const short* xg_s = (const short*)xg;
  unsigned px0 = 0, px1 = 0, px2 = 0, px3 = 0;   // prefetched xg (raw u16)
  if (tid < 512)
    prefetch_xg(xg_s + ((size_t)gb << 9) + dg, &px0, &px1, &px2, &px3);  // t=0

  __syncthreads();   // s_h zeros visible; prefetch in flight

  for (int t = 0; t < T_; t++) {
    const int cur = t & 1;

    // Fused poll+stage (tid<512): wait on the flag of the (dim-block, wave)
    // that produced this thread's 16B slice, then load it. The poll's
    // vmcnt(0) also retires our xg prefetch (issued one step ago -> free).
    if (tid < 512) {
      const unsigned* fp = ctl + g * 64 + ((tid & 63) >> 3) * 8 + nb;
      while (ld_u32_llc(fp) < (unsigned)t) {}
      f32x4 hv = ld_b128_llc((const short*)hbuf + (size_t)cur * (B_ * H_) +
                             (size_t)(g * 8) * H_ + tid * 8);
      *(f32x4*)&s_h[nb][(tid & 63) * 8] = hv;
    }
    __syncthreads();   // S1: staging complete (+ fences prev-step s_pre reads)

    // MFMA: wave wv's M-tile vs all 16 batch columns (8 real + 8 zero)
    f32x4 acc0 = (f32x4){0.f, 0.f, 0.f, 0.f};
    f32x4 acc1 = (f32x4){0.f, 0.f, 0.f, 0.f};
#pragma unroll
    for (int ks = 0; ks < 16; ks += 2) {
      V16 b0, b1;
      b0.f = *(const f32x4*)&s_h[ln15][quad * 8 + ks * 32];
      b1.f = *(const f32x4*)&s_h[ln15][quad * 8 + (ks + 1) * 32];
      acc0 = __builtin_amdgcn_mfma_f32_16x16x32_bf16(areg[ks].b,     b0.b, acc0, 0, 0, 0);
      acc1 = __builtin_amdgcn_mfma_f32_16x16x32_bf16(areg[ks + 1].b, b1.b, acc1, 0, 0, 0);
    }
    const f32x4 accs = acc0 + acc1;

    // C rows m=quad*4+r -> local dim (wv&3)*16+quad*4+r; col = batch (ln15<8)
    if (ln15 < 8)
      *(f32x4*)&s_pre[wv >> 2][ln15][(wv & 3) * 16 + quad * 4] = accs;
    __syncthreads();   // S2: preactivations complete (+ fences s_h MFMA reads)

    if (tid < 512) {
      const float pi = s_pre[0][nb][nd] + bias_i + __uint_as_float(px0 << 16);
      const float pf = s_pre[1][nb][nd] + bias_f + __uint_as_float(px1 << 16);
      const float pg = s_pre[2][nb][nd] + bias_g + __uint_as_float(px2 << 16);
      const float po = s_pre[3][nb][nd] + bias_o + __uint_as_float(px3 << 16);
      const float i_ = sigmoid_(pi), f_ = sigmoid_(pf);
      const float g_ = tanh_(pg),    o_ = sigmoid_(po);
      c = f_ * c + i_ * g_;
      const float h = o_ * tanh_(c);
      if (t < T_ - 1) {
        st_u16_llc((short*)hbuf + (size_t)(cur ^ 1) * (B_ * H_) + (size_t)gb * H_ + dg,
                   (unsigned)(unsigned short)f2bf(h));
        asm volatile("s_waitcnt vmcnt(0)" ::: "memory");   // own-wave h drain
        if ((tid & 63) == 0)
          st_u32_llc(ctl + g * 64 + pd * 8 + nb, (unsigned)(t + 1));
      } else {
        st_f32_llc(hT + gb * H_ + dg, h);
      }
      // xg prefetch for step t+1 (after flag: keeps it off the drain path;
      // next poll's vmcnt(0) absorbs its latency while waiting on peers)
      const int tt = (t + 1 < T_) ? t + 1 : 0;
      prefetch_xg(xg_s + (size_t)tt * (G4_ * B_) + ((size_t)gb << 9) + dg,
                  &px0, &px1, &px2, &px3);
    }
    // no end-of-step barrier: per-wave flags + S1/S2 fence all shared state
  }

  // Final handshake: drain hT (and stray prefetch), then per-block flag.
  asm volatile("s_waitcnt vmcnt(0)" ::: "memory");
  __syncthreads();
  if (tid == 0)
    __hip_atomic_store(ctl + 576 + blk, 1u, __ATOMIC_RELAXED, __HIP_MEMORY_SCOPE_AGENT);

  // Phase 3: fp32 FC by block 0
  if (blk == 0) {
    if (tid < 64)
      while (__hip_atomic_load(ctl + 576 + tid, __ATOMIC_RELAXED, __HIP_MEMORY_SCOPE_AGENT) < 1u) {}
    __builtin_amdgcn_fence(__ATOMIC_ACQUIRE, "agent");
    __syncthreads();
    if (tid < B_ * C_) {
      const int b = tid >> 2, cl = tid & 3;
      const f32x4* hr = (const f32x4*)(hT + b * H_);
      const f32x4* wr = (const f32x4*)(W_fc + cl * H_);
      float s = 0.f;
      for (int d4 = 0; d4 < H_ / 4; d4++) {
        const f32x4 hv = hr[d4];
        const f32x4 wv4 = wr[d4];
        s += hv[0] * wv4[0] + hv[1] * wv4[1] + hv[2] * wv4[2] + hv[3] * wv4[3];
      }
      s += b_fc[cl];
      out[tid] = s;
    }
  }
}

// ---------------------------------------------------------------------------
// Workspace map:
//   [0, 4096)            : ctl words — per-wave step flags [0,512),
//                          final flags [576,640) (all zeroed every launch)
//   [4096, 135168)       : hbuf[2][64][512] bf16 (zeroed = h0)
//   [135168, 266240)     : hT[64][512] fp32
//   [397312, 134615040)  : xg[T][4][B][512] bf16 (128 MiB)
// ---------------------------------------------------------------------------
extern "C" void kernel_launch(void* const* d_in, const int* in_sizes, int n_in,
                              void* d_out, int out_size, void* d_ws, size_t ws_size,
                              hipStream_t stream) {
  const int*   x    = (const int*)d_in[0];
  const float* emb  = (const float*)d_in[1];
  const float* W_ih = (const float*)d_in[2];
  const float* W_hh = (const float*)d_in[3];
  const float* b_ih = (const float*)d_in[4];
  const float* b_hh = (const float*)d_in[5];
  const float* W_fc = (const float*)d_in[6];
  const float* b_fc = (const float*)d_in[7];
  float* out = (float*)d_out;

  char* ws = (char*)d_ws;
  const size_t XG_OFF = 397312;
  const size_t NEEDED = XG_OFF + (size_t)T_ * G4_ * B_ * 2;
  if (ws_size < NEEDED) return;

  unsigned int*   ctl  = (unsigned int*)ws;
  __hip_bfloat16* hbuf = (__hip_bfloat16*)(ws + 4096);
  float*          hT   = (float*)(ws + 135168);
  __hip_bfloat16* xg   = (__hip_bfloat16*)(ws + XG_OFF);

  // zero ctl + both h buffers + hT
  (void)hipMemsetAsync(ws, 0, 266240, stream);

  xg_kernel<<<T_, 256, 0, stream>>>(x, emb, W_ih, xg);
  lstm_kernel<<<64, 1024, 0, stream>>>(W_hh, b_ih, b_hh, W_fc, b_fc, xg,
                                       ctl, hbuf, hT, out);
}

// Round 9
// 1342.770 us; speedup vs baseline: 2.4588x; 2.4588x over previous
//
#include <hip/hip_runtime.h>
#include <hip/hip_bf16.h>

// Problem constants
#define B_  64
#define T_  512
#define E_  256
#define H_  512
#define G4_ 2048
#define C_  4

typedef __attribute__((ext_vector_type(4))) float  f32x4;
typedef __attribute__((ext_vector_type(8))) __bf16 bf16x8;
typedef __attribute__((ext_vector_type(8))) short  short8;   // no HIP builtin 'short8'
typedef __attribute__((ext_vector_type(4))) short  s16x4;    // HIP predefines 'short4'

union V16 { f32x4 f; bf16x8 b; short8 s; };

__device__ __forceinline__ float sigmoid_(float x) { return 1.0f / (1.0f + __expf(-x)); }
__device__ __forceinline__ float tanh_(float x)    { return 1.0f - 2.0f / (__expf(2.0f * x) + 1.0f); }

// Deterministic RNE fp32 -> bf16
__device__ __forceinline__ short f2bf(float f) {
  union { float f; unsigned u; } v; v.f = f;
  return (short)((v.u + 0x7FFFu + ((v.u >> 16) & 1u)) >> 16);
}

// --- per-access LLC-coherent ops (sc0 sc1 = bypass L1+L2, coherent point) ---
__device__ __forceinline__ void store_short_llc(void* p, unsigned v) {
  asm volatile("global_store_short %0, %1, off sc0 sc1" :: "v"(p), "v"(v) : "memory");
}
__device__ __forceinline__ void store_dword_llc(void* p, float v) {
  asm volatile("global_store_dword %0, %1, off sc0 sc1" :: "v"(p), "v"(v) : "memory");
}
// two pipelined coherent 16B loads + single drain
__device__ __forceinline__ void load2_dwordx4_llc(const void* p0, const void* p1,
                                                  f32x4* a, f32x4* b) {
  asm volatile(
      "global_load_dwordx4 %0, %2, off sc0 sc1\n\t"
      "global_load_dwordx4 %1, %3, off sc0 sc1\n\t"
      "s_waitcnt vmcnt(0)"
      : "=&v"(*a), "=&v"(*b) : "v"(p0), "v"(p1) : "memory");
}

// ---------------------------------------------------------------------------
// One-time W_ih fp32 -> bf16 converter (runs every launch; 1 MB out).
// Removes per-xg-block weight conversion (512x redundant).
// ---------------------------------------------------------------------------
__global__ __launch_bounds__(256, 1) void wih_conv(const float* __restrict__ W,
                                                   short* __restrict__ out) {
  const int i = (blockIdx.x * 256 + threadIdx.x) * 4;   // grid 512 -> 524288 elems
  f32x4 v = *(const f32x4*)(W + i);
  s16x4 s;
  s[0] = f2bf(v[0]); s[1] = f2bf(v[1]); s[2] = f2bf(v[2]); s[3] = f2bf(v[3]);
  *(s16x4*)(out + i) = s;
}

// ---------------------------------------------------------------------------
// Phase 1: xg[t][g][b][d] = (emb[x[b][t]] @ W_ih^T)[g*512+d]  (bias added later)
// Templated on weight dtype: WBF16=true loads pre-converted bf16 fragments
// directly (b128 from L2, no f2bf); false = r5-proven fp32 path (fallback
// when ws_size can't hold the converted table).
// ---------------------------------------------------------------------------
template<bool WBF16>
__global__ __launch_bounds__(256, 1) void xg_kernel(
    const int* __restrict__ x, const float* __restrict__ emb,
    const void* __restrict__ Wv,
    __hip_bfloat16* __restrict__ xg)
{
  const int t   = blockIdx.x;
  const int tid = threadIdx.x;
  __shared__ int s_idx[B_];
  __shared__ __hip_bfloat16 s_e[B_][E_ + 8];

  if (tid < B_) s_idx[tid] = x[tid * T_ + t];
  __syncthreads();
  {
    int b = tid >> 2, ch = tid & 3;
    const float* src = emb + (size_t)s_idx[b] * E_ + ch * 64;
    short* dst = (short*)&s_e[b][ch * 64];
#pragma unroll
    for (int i = 0; i < 16; i++) {
      f32x4 v = *(const f32x4*)(src + i * 4);
      s16x4 s;
      s[0] = f2bf(v[0]); s[1] = f2bf(v[1]); s[2] = f2bf(v[2]); s[3] = f2bf(v[3]);
      *(s16x4*)(dst + i * 4) = s;
    }
  }
  __syncthreads();

  const int wv   = tid >> 6;
  const int lane = tid & 63;
  const int ln15 = lane & 15, quad = lane >> 4;

  V16 breg[4][8];
#pragma unroll
  for (int nt = 0; nt < 4; nt++)
#pragma unroll
    for (int ks = 0; ks < 8; ks++)
      breg[nt][ks].f = *(const f32x4*)(&s_e[nt * 16 + ln15][quad * 8 + ks * 32]);

  const int gbase = wv * 512;
  const size_t base_t = (size_t)t * (G4_ * B_);
  for (int mt = 0; mt < 32; mt++) {
    const int grow = gbase + mt * 16 + ln15;
    V16 areg[8];
    if constexpr (WBF16) {
      const short* arow = (const short*)Wv + (size_t)grow * E_ + quad * 8;
#pragma unroll
      for (int ks = 0; ks < 8; ks++)
        areg[ks].f = *(const f32x4*)(arow + ks * 32);
    } else {
      const float* arow = (const float*)Wv + (size_t)grow * E_ + quad * 8;
#pragma unroll
      for (int ks = 0; ks < 8; ks++) {
        f32x4 lo = *(const f32x4*)(arow + ks * 32);
        f32x4 hi = *(const f32x4*)(arow + ks * 32 + 4);
        short8 s;
        s[0] = f2bf(lo[0]); s[1] = f2bf(lo[1]); s[2] = f2bf(lo[2]); s[3] = f2bf(lo[3]);
        s[4] = f2bf(hi[0]); s[5] = f2bf(hi[1]); s[6] = f2bf(hi[2]); s[7] = f2bf(hi[3]);
        areg[ks].s = s;
      }
    }

    f32x4 acc[4];
#pragma unroll
    for (int nt = 0; nt < 4; nt++) acc[nt] = (f32x4){0.f, 0.f, 0.f, 0.f};
#pragma unroll
    for (int ks = 0; ks < 8; ks++)
#pragma unroll
      for (int nt = 0; nt < 4; nt++)
        acc[nt] = __builtin_amdgcn_mfma_f32_16x16x32_bf16(areg[ks].b, breg[nt][ks].b, acc[nt], 0, 0, 0);

    const int dbase = mt * 16 + quad * 4;
#pragma unroll
    for (int nt = 0; nt < 4; nt++) {
      const int batch = nt * 16 + ln15;
      s16x4 sv;
#pragma unroll
      for (int r = 0; r < 4; r++) sv[r] = f2bf(acc[nt][r]);
      *(s16x4*)((short*)xg + base_t + ((size_t)wv << 15) + ((size_t)batch << 9) + dbase) = sv;
    }
  }
}

// ---------------------------------------------------------------------------
// Phase 2: persistent recurrent kernel — VERBATIM r5 (measured 1183 us; best
// of r5-r8; r6/r7/r8 restructures all regressed or hung). 64 blocks x 512
// threads; group = 16 blocks; 16 thin pollers on one flag line; LDS-staged h;
// 4 barriers/step; per-access sc0sc1 coherence.
// ---------------------------------------------------------------------------
__global__ __launch_bounds__(512, 2) void lstm_kernel(
    const float* __restrict__ W_hh,
    const float* __restrict__ b_ih, const float* __restrict__ b_hh,
    const float* __restrict__ W_fc, const float* __restrict__ b_fc,
    const __hip_bfloat16* __restrict__ xg,
    unsigned int* flags, __hip_bfloat16* hbuf /*[2][64][512]*/, float* hT,
    float* out)
{
  const int tid  = threadIdx.x;
  const int blk  = blockIdx.x;
  const int pb   = blk & 3;        // batch group
  const int pd   = blk >> 2;       // dim slice [pd*32, +32)
  const int d0   = pd * 32;
  const int wv   = tid >> 6;       // 0..7
  const int lane = tid & 63;
  const int ln15 = lane & 15, quad = lane >> 4;

  __shared__ __hip_bfloat16 s_h[16][520];      // h_t for our 16 batches (+8 pad)
  __shared__ float s_pre[4][16][36];           // [gate][batch][dim(+4 pad)]

  // Register-resident bf16 A fragments from fp32 W_hh.
  V16 areg[16];
  {
    const int grow = (wv >> 1) * 512 + d0 + (wv & 1) * 16 + ln15;
    const float* ap = W_hh + (size_t)grow * H_ + quad * 8;
#pragma unroll
    for (int ks = 0; ks < 16; ks++) {
      f32x4 lo = *(const f32x4*)(ap + ks * 32);
      f32x4 hi = *(const f32x4*)(ap + ks * 32 + 4);
      short8 s;
      s[0] = f2bf(lo[0]); s[1] = f2bf(lo[1]); s[2] = f2bf(lo[2]); s[3] = f2bf(lo[3]);
      s[4] = f2bf(hi[0]); s[5] = f2bf(hi[1]); s[6] = f2bf(hi[2]); s[7] = f2bf(hi[3]);
      areg[ks].s = s;
    }
  }

  // Gate-math mapping: one cell per thread (16 batches x 32 dims = 512)
  const int nb = tid >> 5;         // 0..15
  const int nd = tid & 31;         // 0..31
  const int gb = pb * 16 + nb;     // global batch
  const int dg = d0 + nd;          // global h-dim
  const float bias_i = b_ih[dg]        + b_hh[dg];
  const float bias_f = b_ih[512 + dg]  + b_hh[512 + dg];
  const float bias_g = b_ih[1024 + dg] + b_hh[1024 + dg];
  const float bias_o = b_ih[1536 + dg] + b_hh[1536 + dg];
  float c = 0.0f;
  const int myflag = pb * 16 + pd;

  for (int t = 0; t < T_; t++) {
    const int cur = t & 1, nxt = cur ^ 1;

    // xg prefetch (plain cached loads; independent of h)
    const size_t xoff = (size_t)t * (G4_ * B_) + ((size_t)gb << 9) + dg;
    const __hip_bfloat16 xgi = xg[xoff];
    const __hip_bfloat16 xgf = xg[xoff + (1u << 15)];
    const __hip_bfloat16 xgg = xg[xoff + (2u << 15)];
    const __hip_bfloat16 xgo = xg[xoff + (3u << 15)];

    // Wait for all 16 producers of our batch group's h_t (flag >= t).
    if (tid < 16) {
      const unsigned* fp = flags + pb * 16 + tid;
      while (__hip_atomic_load(fp, __ATOMIC_RELAXED, __HIP_MEMORY_SCOPE_AGENT) < (unsigned)t) {}
    }
    __syncthreads();   // S1: h_t visible for everyone

    // Stage h_t -> LDS: 16 KB via 2 coherent 16B loads/thread, coalesced.
    {
      const short* hbase = (const short*)hbuf + (size_t)cur * (B_ * H_) + (size_t)(pb * 16) * H_;
      const int i0 = tid, i1 = tid + 512;
      f32x4 va, vb;
      load2_dwordx4_llc(hbase + i0 * 8, hbase + i1 * 8, &va, &vb);
      *(f32x4*)&s_h[i0 >> 6][(i0 & 63) * 8] = va;
      *(f32x4*)&s_h[i1 >> 6][(i1 & 63) * 8] = vb;
    }
    __syncthreads();   // S2: LDS staging complete

    // B fragments from LDS; 16 MFMAs on 2 accumulator chains.
    f32x4 acc0 = (f32x4){0.f, 0.f, 0.f, 0.f};
    f32x4 acc1 = (f32x4){0.f, 0.f, 0.f, 0.f};
#pragma unroll
    for (int ks = 0; ks < 16; ks += 2) {
      V16 b0, b1;
      b0.f = *(const f32x4*)&s_h[ln15][quad * 8 + ks * 32];
      b1.f = *(const f32x4*)&s_h[ln15][quad * 8 + (ks + 1) * 32];
      acc0 = __builtin_amdgcn_mfma_f32_16x16x32_bf16(areg[ks].b,     b0.b, acc0, 0, 0, 0);
      acc1 = __builtin_amdgcn_mfma_f32_16x16x32_bf16(areg[ks + 1].b, b1.b, acc1, 0, 0, 0);
    }
    const f32x4 accs = acc0 + acc1;

    // Scatter: C row m=quad*4+r -> d_local=(wv&1)*16+quad*4+r
    *(f32x4*)&s_pre[wv >> 1][ln15][(wv & 1) * 16 + quad * 4] = accs;
    __syncthreads();   // S3: preactivations complete

    {
      const float pi = s_pre[0][nb][nd] + bias_i + __bfloat162float(xgi);
      const float pf = s_pre[1][nb][nd] + bias_f + __bfloat162float(xgf);
      const float pg = s_pre[2][nb][nd] + bias_g + __bfloat162float(xgg);
      const float po = s_pre[3][nb][nd] + bias_o + __bfloat162float(xgo);
      const float i_ = sigmoid_(pi), f_ = sigmoid_(pf);
      const float g_ = tanh_(pg),    o_ = sigmoid_(po);
      c = f_ * c + i_ * g_;
      const float h = o_ * tanh_(c);
      if (t < T_ - 1) {
        store_short_llc((short*)hbuf + (size_t)nxt * (B_ * H_) + (size_t)gb * H_ + dg,
                        (unsigned)(unsigned short)f2bf(h));
      } else {
        store_dword_llc(hT + gb * H_ + dg, h);
      }
    }
    __syncthreads();   // S4: vmcnt(0) drain -> h stores acked at LLC

    if (tid == 0)
      __hip_atomic_store(&flags[myflag], (unsigned)(t + 1),
                         __ATOMIC_RELAXED, __HIP_MEMORY_SCOPE_AGENT);
  }

  // Phase 3: fp32 FC by block 0 (poll ALL 64 flags == T)
  if (blk == 0) {
    if (tid < 64)
      while (__hip_atomic_load(&flags[tid], __ATOMIC_RELAXED, __HIP_MEMORY_SCOPE_AGENT) < (unsigned)T_) {}
    __builtin_amdgcn_fence(__ATOMIC_ACQUIRE, "agent");
    __syncthreads();
    for (int o = tid; o < B_ * C_; o += 512) {
      const int b = o >> 2, cl = o & 3;
      const f32x4* hr = (const f32x4*)(hT + b * H_);
      const f32x4* wr = (const f32x4*)(W_fc + cl * H_);
      float s = 0.f;
      for (int d4 = 0; d4 < H_ / 4; d4++) {
        const f32x4 hv = hr[d4];
        const f32x4 wv4 = wr[d4];
        s += hv[0] * wv4[0] + hv[1] * wv4[1] + hv[2] * wv4[2] + hv[3] * wv4[3];
      }
      s += b_fc[cl];
      out[o] = s;
    }
  }
}

// ---------------------------------------------------------------------------
// Workspace map:
//   [0, 1024)            : flags[256] (uint32, zeroed every launch)
//   [4096, 135168)       : hbuf[2][64][512] bf16 (both buffers zeroed = h0)
//   [135168, 266240)     : hT[64][512] fp32
//   [524288, 134742016)  : xg[T][4][B][512] bf16 (128 MiB)
//   [134742016, 135790592): W_ih bf16 table (1 MiB) — only if ws_size allows
// ---------------------------------------------------------------------------
extern "C" void kernel_launch(void* const* d_in, const int* in_sizes, int n_in,
                              void* d_out, int out_size, void* d_ws, size_t ws_size,
                              hipStream_t stream) {
  const int*   x    = (const int*)d_in[0];
  const float* emb  = (const float*)d_in[1];
  const float* W_ih = (const float*)d_in[2];
  const float* W_hh = (const float*)d_in[3];
  const float* b_ih = (const float*)d_in[4];
  const float* b_hh = (const float*)d_in[5];
  const float* W_fc = (const float*)d_in[6];
  const float* b_fc = (const float*)d_in[7];
  float* out = (float*)d_out;

  char* ws = (char*)d_ws;
  const size_t XG_OFF  = 524288;
  const size_t XG_END  = XG_OFF + (size_t)T_ * G4_ * B_ * 2;   // 134,742,016
  const size_t NEEDED2 = XG_END + (size_t)G4_ * E_ * 2;        // +1 MiB bf16 W_ih
  if (ws_size < XG_END) return;

  unsigned int*   flags = (unsigned int*)ws;
  __hip_bfloat16* hbuf  = (__hip_bfloat16*)(ws + 4096);
  float*          hT    = (float*)(ws + 135168);
  __hip_bfloat16* xg    = (__hip_bfloat16*)(ws + XG_OFF);
  short*          wih16 = (short*)(ws + XG_END);

  (void)hipMemsetAsync(ws, 0, 135168, stream);

  if (ws_size >= NEEDED2) {
    wih_conv<<<512, 256, 0, stream>>>(W_ih, wih16);
    xg_kernel<true><<<T_, 256, 0, stream>>>(x, emb, wih16, xg);
  } else {
    xg_kernel<false><<<T_, 256, 0, stream>>>(x, emb, W_ih, xg);
  }
  lstm_kernel<<<64, 512, 0, stream>>>(W_hh, b_ih, b_hh, W_fc, b_fc, xg,
                                      flags, hbuf, hT, out);
}

// Round 10
// 1251.375 us; speedup vs baseline: 2.6384x; 1.0730x over previous
//
#include <hip/hip_runtime.h>
#include <hip/hip_bf16.h>

// Problem constants
#define B_  64
#define T_  512
#define E_  256
#define H_  512
#define G4_ 2048
#define C_  4

typedef __attribute__((ext_vector_type(4))) float  f32x4;
typedef __attribute__((ext_vector_type(8))) __bf16 bf16x8;
typedef __attribute__((ext_vector_type(8))) short  short8;   // no HIP builtin 'short8'
typedef __attribute__((ext_vector_type(4))) short  s16x4;    // HIP predefines 'short4'

union V16 { f32x4 f; bf16x8 b; short8 s; };

__device__ __forceinline__ float sigmoid_(float x) { return 1.0f / (1.0f + __expf(-x)); }
__device__ __forceinline__ float tanh_(float x)    { return 1.0f - 2.0f / (__expf(2.0f * x) + 1.0f); }

// Deterministic RNE fp32 -> bf16
__device__ __forceinline__ short f2bf(float f) {
  union { float f; unsigned u; } v; v.f = f;
  return (short)((v.u + 0x7FFFu + ((v.u >> 16) & 1u)) >> 16);
}

// --- per-access LLC-coherent ops (sc0 sc1 = bypass L1+L2, coherent point) ---
__device__ __forceinline__ void store_short_llc(void* p, unsigned v) {
  asm volatile("global_store_short %0, %1, off sc0 sc1" :: "v"(p), "v"(v) : "memory");
}
__device__ __forceinline__ void store_dword_llc(void* p, float v) {
  asm volatile("global_store_dword %0, %1, off sc0 sc1" :: "v"(p), "v"(v) : "memory");
}
// one coherent 16B load + drain (staging)
__device__ __forceinline__ f32x4 ld_b128_llc(const void* p) {
  f32x4 v;
  asm volatile("global_load_dwordx4 %0, %1, off sc0 sc1\n\ts_waitcnt vmcnt(0)"
               : "=&v"(v) : "v"(p) : "memory");
  return v;
}

// ---------------------------------------------------------------------------
// One-time W_ih fp32 -> bf16 converter (r9 win: removes 512x redundant
// per-xg-block conversion).
// ---------------------------------------------------------------------------
__global__ __launch_bounds__(256, 1) void wih_conv(const float* __restrict__ W,
                                                   short* __restrict__ out) {
  const int i = (blockIdx.x * 256 + threadIdx.x) * 4;   // grid 512 -> 524288 elems
  f32x4 v = *(const f32x4*)(W + i);
  s16x4 s;
  s[0] = f2bf(v[0]); s[1] = f2bf(v[1]); s[2] = f2bf(v[2]); s[3] = f2bf(v[3]);
  *(s16x4*)(out + i) = s;
}

// ---------------------------------------------------------------------------
// Phase 1: xg[t][g][b][d] — unchanged from r9 (measured win).
// ---------------------------------------------------------------------------
template<bool WBF16>
__global__ __launch_bounds__(256, 1) void xg_kernel(
    const int* __restrict__ x, const float* __restrict__ emb,
    const void* __restrict__ Wv,
    __hip_bfloat16* __restrict__ xg)
{
  const int t   = blockIdx.x;
  const int tid = threadIdx.x;
  __shared__ int s_idx[B_];
  __shared__ __hip_bfloat16 s_e[B_][E_ + 8];

  if (tid < B_) s_idx[tid] = x[tid * T_ + t];
  __syncthreads();
  {
    int b = tid >> 2, ch = tid & 3;
    const float* src = emb + (size_t)s_idx[b] * E_ + ch * 64;
    short* dst = (short*)&s_e[b][ch * 64];
#pragma unroll
    for (int i = 0; i < 16; i++) {
      f32x4 v = *(const f32x4*)(src + i * 4);
      s16x4 s;
      s[0] = f2bf(v[0]); s[1] = f2bf(v[1]); s[2] = f2bf(v[2]); s[3] = f2bf(v[3]);
      *(s16x4*)(dst + i * 4) = s;
    }
  }
  __syncthreads();

  const int wv   = tid >> 6;
  const int lane = tid & 63;
  const int ln15 = lane & 15, quad = lane >> 4;

  V16 breg[4][8];
#pragma unroll
  for (int nt = 0; nt < 4; nt++)
#pragma unroll
    for (int ks = 0; ks < 8; ks++)
      breg[nt][ks].f = *(const f32x4*)(&s_e[nt * 16 + ln15][quad * 8 + ks * 32]);

  const int gbase = wv * 512;
  const size_t base_t = (size_t)t * (G4_ * B_);
  for (int mt = 0; mt < 32; mt++) {
    const int grow = gbase + mt * 16 + ln15;
    V16 areg[8];
    if constexpr (WBF16) {
      const short* arow = (const short*)Wv + (size_t)grow * E_ + quad * 8;
#pragma unroll
      for (int ks = 0; ks < 8; ks++)
        areg[ks].f = *(const f32x4*)(arow + ks * 32);
    } else {
      const float* arow = (const float*)Wv + (size_t)grow * E_ + quad * 8;
#pragma unroll
      for (int ks = 0; ks < 8; ks++) {
        f32x4 lo = *(const f32x4*)(arow + ks * 32);
        f32x4 hi = *(const f32x4*)(arow + ks * 32 + 4);
        short8 s;
        s[0] = f2bf(lo[0]); s[1] = f2bf(lo[1]); s[2] = f2bf(lo[2]); s[3] = f2bf(lo[3]);
        s[4] = f2bf(hi[0]); s[5] = f2bf(hi[1]); s[6] = f2bf(hi[2]); s[7] = f2bf(hi[3]);
        areg[ks].s = s;
      }
    }

    f32x4 acc[4];
#pragma unroll
    for (int nt = 0; nt < 4; nt++) acc[nt] = (f32x4){0.f, 0.f, 0.f, 0.f};
#pragma unroll
    for (int ks = 0; ks < 8; ks++)
#pragma unroll
      for (int nt = 0; nt < 4; nt++)
        acc[nt] = __builtin_amdgcn_mfma_f32_16x16x32_bf16(areg[ks].b, breg[nt][ks].b, acc[nt], 0, 0, 0);

    const int dbase = mt * 16 + quad * 4;
#pragma unroll
    for (int nt = 0; nt < 4; nt++) {
      const int batch = nt * 16 + ln15;
      s16x4 sv;
#pragma unroll
      for (int r = 0; r < 4; r++) sv[r] = f2bf(acc[nt][r]);
      *(s16x4*)((short*)xg + base_t + ((size_t)wv << 15) + ((size_t)batch << 9) + dbase) = sv;
    }
  }
}

// ---------------------------------------------------------------------------
// Phase 2: persistent recurrent kernel — r5's proven 4-barrier thin-poll
// skeleton, regrouped 8x8: group g = blk&7 owns batches [g*8,+8); dim-block
// pd = blk>>3 owns dims [pd*64,+64). Sync domain = 8 blocks (was 16);
// 8 flags on one dedicated line, polled by 8 threads; stage = 8 KB/block-step
// (was 16 KB). Wave wv: gate wv>>1, dim-half (wv&1)*32, two M-tiles -> 128
// VGPR register-resident W_hh, 32 MFMAs/wave vs 16 zero-padded batch cols.
// ---------------------------------------------------------------------------
__global__ __launch_bounds__(512, 2) void lstm_kernel(
    const float* __restrict__ W_hh,
    const float* __restrict__ b_ih, const float* __restrict__ b_hh,
    const float* __restrict__ W_fc, const float* __restrict__ b_fc,
    const __hip_bfloat16* __restrict__ xg,
    unsigned int* flags, __hip_bfloat16* hbuf /*[2][64][512]*/, float* hT,
    float* out)
{
  const int tid  = threadIdx.x;
  const int blk  = blockIdx.x;
  const int g    = blk & 7;        // batch group (8 batches)
  const int pd   = blk >> 3;       // dim slice [pd*64, +64)
  const int d0   = pd * 64;
  const int wv   = tid >> 6;       // 0..7
  const int lane = tid & 63;
  const int ln15 = lane & 15, quad = lane >> 4;

  __shared__ __hip_bfloat16 s_h[16][520];   // rows 0-7: batches; 8-15: zeros
  __shared__ float s_pre[4][8][68];         // [gate][batch][dim(+4 pad)]

  // Register-resident bf16 A fragments (two M-tiles per wave).
  const int gate  = wv >> 1;
  const int dhalf = (wv & 1) * 32;
  V16 areg[2][16];
#pragma unroll
  for (int tau = 0; tau < 2; tau++) {
    const int grow = gate * 512 + d0 + dhalf + tau * 16 + ln15;
    const float* ap = W_hh + (size_t)grow * H_ + quad * 8;
#pragma unroll
    for (int ks = 0; ks < 16; ks++) {
      f32x4 lo = *(const f32x4*)(ap + ks * 32);
      f32x4 hi = *(const f32x4*)(ap + ks * 32 + 4);
      short8 s;
      s[0] = f2bf(lo[0]); s[1] = f2bf(lo[1]); s[2] = f2bf(lo[2]); s[3] = f2bf(lo[3]);
      s[4] = f2bf(hi[0]); s[5] = f2bf(hi[1]); s[6] = f2bf(hi[2]); s[7] = f2bf(hi[3]);
      areg[tau][ks].s = s;
    }
  }

  // Gate-math mapping: one cell per thread (8 batches x 64 dims = 512)
  const int nb = tid >> 6;         // 0..7  (== wv)
  const int nd = tid & 63;         // 0..63
  const int gb = g * 8 + nb;       // global batch
  const int dg = d0 + nd;          // global h-dim
  const float bias_i = b_ih[dg]        + b_hh[dg];
  const float bias_f = b_ih[512 + dg]  + b_hh[512 + dg];
  const float bias_g = b_ih[1024 + dg] + b_hh[1024 + dg];
  const float bias_o = b_ih[1536 + dg] + b_hh[1536 + dg];
  float c = 0.0f;
  const int myflag = g * 16 + pd;  // each group's 8 flags on their own line

  // zero s_h rows 8..15 once (N-cols 8..15 multiply against zeros);
  // first-iteration S2 orders this before any MFMA read.
  *(f32x4*)&s_h[8 + (tid >> 6)][(tid & 63) * 8] = (f32x4){0.f, 0.f, 0.f, 0.f};

  for (int t = 0; t < T_; t++) {
    const int cur = t & 1, nxt = cur ^ 1;

    // xg prefetch (plain cached loads; independent of h)
    const size_t xoff = (size_t)t * (G4_ * B_) + ((size_t)gb << 9) + dg;
    const __hip_bfloat16 xgi = xg[xoff];
    const __hip_bfloat16 xgf = xg[xoff + (1u << 15)];
    const __hip_bfloat16 xgg = xg[xoff + (2u << 15)];
    const __hip_bfloat16 xgo = xg[xoff + (3u << 15)];

    // Wait for all 8 producers of our group's h_t (flag >= t). Thin poll.
    if (tid < 8) {
      const unsigned* fp = flags + g * 16 + tid;
      while (__hip_atomic_load(fp, __ATOMIC_RELAXED, __HIP_MEMORY_SCOPE_AGENT) < (unsigned)t) {}
    }
    __syncthreads();   // S1: h_t visible for everyone

    // Stage h_t -> LDS: 8 KB via 1 coherent 16B load/thread, coalesced.
    {
      const short* hbase = (const short*)hbuf + (size_t)cur * (B_ * H_) + (size_t)(g * 8) * H_;
      f32x4 va = ld_b128_llc(hbase + tid * 8);
      *(f32x4*)&s_h[tid >> 6][(tid & 63) * 8] = va;
    }
    __syncthreads();   // S2: LDS staging complete

    // B fragments from LDS; 32 MFMAs on 2 chains, breg shared across tiles.
    f32x4 acc0 = (f32x4){0.f, 0.f, 0.f, 0.f};
    f32x4 acc1 = (f32x4){0.f, 0.f, 0.f, 0.f};
#pragma unroll
    for (int ks = 0; ks < 16; ks++) {
      V16 b0;
      b0.f = *(const f32x4*)&s_h[ln15][quad * 8 + ks * 32];
      acc0 = __builtin_amdgcn_mfma_f32_16x16x32_bf16(areg[0][ks].b, b0.b, acc0, 0, 0, 0);
      acc1 = __builtin_amdgcn_mfma_f32_16x16x32_bf16(areg[1][ks].b, b0.b, acc1, 0, 0, 0);
    }

    // Scatter: tile tau, C row m=quad*4+r -> local dim dhalf+tau*16+quad*4+r
    if (ln15 < 8) {
      *(f32x4*)&s_pre[gate][ln15][dhalf + quad * 4]      = acc0;
      *(f32x4*)&s_pre[gate][ln15][dhalf + 16 + quad * 4] = acc1;
    }
    __syncthreads();   // S3: preactivations complete

    {
      const float pi = s_pre[0][nb][nd] + bias_i + __bfloat162float(xgi);
      const float pf = s_pre[1][nb][nd] + bias_f + __bfloat162float(xgf);
      const float pg = s_pre[2][nb][nd] + bias_g + __bfloat162float(xgg);
      const float po = s_pre[3][nb][nd] + bias_o + __bfloat162float(xgo);
      const float i_ = sigmoid_(pi), f_ = sigmoid_(pf);
      const float g_ = tanh_(pg),    o_ = sigmoid_(po);
      c = f_ * c + i_ * g_;
      const float h = o_ * tanh_(c);
      if (t < T_ - 1) {
        store_short_llc((short*)hbuf + (size_t)nxt * (B_ * H_) + (size_t)gb * H_ + dg,
                        (unsigned)(unsigned short)f2bf(h));
      } else {
        store_dword_llc(hT + gb * H_ + dg, h);
      }
    }
    __syncthreads();   // S4: vmcnt(0) drain -> h stores acked at LLC

    if (tid == 0)
      __hip_atomic_store(&flags[myflag], (unsigned)(t + 1),
                         __ATOMIC_RELAXED, __HIP_MEMORY_SCOPE_AGENT);
  }

  // Phase 3: fp32 FC by block 0 (poll all 64 block flags == T)
  if (blk == 0) {
    if (tid < 64)
      while (__hip_atomic_load(flags + (tid >> 3) * 16 + (tid & 7),
                               __ATOMIC_RELAXED, __HIP_MEMORY_SCOPE_AGENT) < (unsigned)T_) {}
    __builtin_amdgcn_fence(__ATOMIC_ACQUIRE, "agent");
    __syncthreads();
    for (int o = tid; o < B_ * C_; o += 512) {
      const int b = o >> 2, cl = o & 3;
      const f32x4* hr = (const f32x4*)(hT + b * H_);
      const f32x4* wr = (const f32x4*)(W_fc + cl * H_);
      float s = 0.f;
      for (int d4 = 0; d4 < H_ / 4; d4++) {
        const f32x4 hv = hr[d4];
        const f32x4 wv4 = wr[d4];
        s += hv[0] * wv4[0] + hv[1] * wv4[1] + hv[2] * wv4[2] + hv[3] * wv4[3];
      }
      s += b_fc[cl];
      out[o] = s;
    }
  }
}

// ---------------------------------------------------------------------------
// Workspace map:
//   [0, 1024)            : flags[256] (uint32; group g's 8 flags at [g*16,+8))
//   [4096, 135168)       : hbuf[2][64][512] bf16 (both buffers zeroed = h0)
//   [135168, 266240)     : hT[64][512] fp32
//   [524288, 134742016)  : xg[T][4][B][512] bf16 (128 MiB)
//   [134742016, 135790592): W_ih bf16 table (1 MiB) — only if ws_size allows
// ---------------------------------------------------------------------------
extern "C" void kernel_launch(void* const* d_in, const int* in_sizes, int n_in,
                              void* d_out, int out_size, void* d_ws, size_t ws_size,
                              hipStream_t stream) {
  const int*   x    = (const int*)d_in[0];
  const float* emb  = (const float*)d_in[1];
  const float* W_ih = (const float*)d_in[2];
  const float* W_hh = (const float*)d_in[3];
  const float* b_ih = (const float*)d_in[4];
  const float* b_hh = (const float*)d_in[5];
  const float* W_fc = (const float*)d_in[6];
  const float* b_fc = (const float*)d_in[7];
  float* out = (float*)d_out;

  char* ws = (char*)d_ws;
  const size_t XG_OFF  = 524288;
  const size_t XG_END  = XG_OFF + (size_t)T_ * G4_ * B_ * 2;   // 134,742,016
  const size_t NEEDED2 = XG_END + (size_t)G4_ * E_ * 2;        // +1 MiB bf16 W_ih
  if (ws_size < XG_END) return;

  unsigned int*   flags = (unsigned int*)ws;
  __hip_bfloat16* hbuf  = (__hip_bfloat16*)(ws + 4096);
  float*          hT    = (float*)(ws + 135168);
  __hip_bfloat16* xg    = (__hip_bfloat16*)(ws + XG_OFF);
  short*          wih16 = (short*)(ws + XG_END);

  (void)hipMemsetAsync(ws, 0, 135168, stream);

  if (ws_size >= NEEDED2) {
    wih_conv<<<512, 256, 0, stream>>>(W_ih, wih16);
    xg_kernel<true><<<T_, 256, 0, stream>>>(x, emb, wih16, xg);
  } else {
    xg_kernel<false><<<T_, 256, 0, stream>>>(x, emb, W_ih, xg);
  }
  lstm_kernel<<<64, 512, 0, stream>>>(W_hh, b_ih, b_hh, W_fc, b_fc, xg,
                                      flags, hbuf, hT, out);
}